// Round 1
// baseline (189.119 us; speedup 1.0000x reference)
//
#include <hip/hip_runtime.h>
#include <hip/hip_bf16.h>
#include <math.h>

#define B_ 64
#define T_ 2048
#define D_ 512
#define U_ 512

typedef __attribute__((ext_vector_type(8))) short short8;
typedef __attribute__((ext_vector_type(4))) float f32x4;

// RNE f32 -> bf16 (no NaN handling needed for this data)
__device__ __forceinline__ unsigned short f2bf(float x) {
  unsigned int u = __float_as_uint(x);
  unsigned int r = u + 0x7fffu + ((u >> 16) & 1u);
  return (unsigned short)(r >> 16);
}

// fast tanh: 1 - 2/(e^{2x}+1), exact limits at +-inf
__device__ __forceinline__ float tanh_fast(float x) {
  float e = __expf(2.f * x);
  return 1.f - 2.f * __builtin_amdgcn_rcpf(e + 1.f);
}

#define SWZ(off, rc) ((off) ^ ((unsigned)((rc) & 7) << 4))

// ---------------- q_proj = query @ W1 + b1 : [64,512] ----------------
__global__ __launch_bounds__(256) void k_qproj(const float* __restrict__ query,
                                               const float* __restrict__ W1,
                                               const float* __restrict__ b1,
                                               float* __restrict__ qproj) {
  const int b = blockIdx.x;
  const int tid = threadIdx.x;
  __shared__ float q[D_];
  q[tid] = query[b * D_ + tid];
  q[tid + 256] = query[b * D_ + tid + 256];
  __syncthreads();
  float a0 = 0.f, a1 = 0.f;
#pragma unroll 8
  for (int d = 0; d < D_; d++) {
    float qd = q[d];
    a0 = fmaf(qd, W1[d * U_ + tid], a0);
    a1 = fmaf(qd, W1[d * U_ + tid + 256], a1);
  }
  qproj[b * U_ + tid] = a0 + b1[tid];
  qproj[b * U_ + tid + 256] = a1 + b1[tid + 256];
}

// ---------------- W2 [k][u] f32 -> w2t [u][k] bf16 ----------------
__global__ __launch_bounds__(256) void k_w2t(const float* __restrict__ W2,
                                             unsigned short* __restrict__ w2t) {
  __shared__ float tile[32][33];
  const int k0 = blockIdx.y * 32, u0 = blockIdx.x * 32;
  const int tx = threadIdx.x, ty = threadIdx.y;  // 32 x 8
#pragma unroll
  for (int r = 0; r < 4; r++)
    tile[ty + 8 * r][tx] = W2[(size_t)(k0 + ty + 8 * r) * U_ + (u0 + tx)];
  __syncthreads();
#pragma unroll
  for (int r = 0; r < 4; r++) {
    int u_l = ty + 8 * r, k_l = tx;
    w2t[(size_t)(u0 + u_l) * D_ + (k0 + k_l)] = f2bf(tile[k_l][u_l]);
  }
}

// ---------------- fused score GEMM ----------------
// score[b,t] = Wv . tanh(qproj[b] + b2 + values[b,t,:] @ W2) + bv ; -inf if row all-zero
// BM=64 rows/block, full U=512 cols, BK=64. 512 threads = 8 waves, wave w owns cols [w*64, w*64+64).
__global__ __launch_bounds__(512, 4) void k_score(
    const float* __restrict__ values, const unsigned short* __restrict__ w2t,
    const float* __restrict__ qproj, const float* __restrict__ b2,
    const float* __restrict__ Wv, const float* __restrict__ bv,
    float* __restrict__ scores) {
  __shared__ __align__(16) unsigned short lsA[64 * 64];    // 8 KB, swizzled [row][k]
  __shared__ __align__(16) unsigned short lsB[U_ * 64];    // 64 KB, swizzled [u][k]
  __shared__ float qp[U_];
  __shared__ float wv_s[U_];
  __shared__ float red[64 * 8];
  __shared__ int rowflag[64];

  const int tid = threadIdx.x;
  const int wid = tid >> 6;     // 0..7
  const int lane = tid & 63;
  const int m0 = blockIdx.x * 64;
  const int b = m0 >> 11;       // T = 2048

  qp[tid] = qproj[b * U_ + tid] + b2[tid];
  wv_s[tid] = Wv[tid];
  if (tid < 64) rowflag[tid] = 0;

  // A staging: thread -> (row, k-chunk of 8)
  const int arow = tid >> 3;   // 0..63
  const int akq = tid & 7;     // 0..7
  const float* aptr = values + (size_t)(m0 + arow) * D_ + akq * 8;
  char* lsAc = (char*)lsA;
  char* lsBc = (char*)lsB;
  const unsigned int aoff = SWZ((unsigned)(arow * 128 + akq * 16), arow);

  f32x4 acc[4][4];
#pragma unroll
  for (int i = 0; i < 4; i++)
#pragma unroll
    for (int j = 0; j < 4; j++) acc[i][j] = (f32x4){0.f, 0.f, 0.f, 0.f};

  const int colbase = wid * 64;
  __syncthreads();

  for (int kk = 0; kk < D_; kk += 64) {
    // ---- stage B: 64KB via global_load_lds, linear dest + inverse-swizzled src
#pragma unroll
    for (int r = 0; r < 8; r++) {
      unsigned int off = (unsigned)tid * 16 + (unsigned)r * 8192;
      unsigned int col = off >> 7;
      unsigned int logical = off ^ ((col & 7u) << 4);
      unsigned int klocal = (logical & 127u) >> 1;
      const unsigned short* src = w2t + (size_t)col * D_ + kk + klocal;
      __builtin_amdgcn_global_load_lds(
          (const __attribute__((address_space(1))) unsigned int*)src,
          (__attribute__((address_space(3))) unsigned int*)(lsBc + (size_t)wid * 1024 + (size_t)r * 8192),
          16, 0, 0);
    }
    // ---- stage A: f32 load, nonzero check, convert, swizzled ds_write_b128
    float4 v0 = *(const float4*)(aptr + kk);
    float4 v1 = *(const float4*)(aptr + kk + 4);
    if (v0.x != 0.f || v0.y != 0.f || v0.z != 0.f || v0.w != 0.f ||
        v1.x != 0.f || v1.y != 0.f || v1.z != 0.f || v1.w != 0.f)
      rowflag[arow] = 1;
    uint4 pk;
    pk.x = (unsigned)f2bf(v0.x) | ((unsigned)f2bf(v0.y) << 16);
    pk.y = (unsigned)f2bf(v0.z) | ((unsigned)f2bf(v0.w) << 16);
    pk.z = (unsigned)f2bf(v1.x) | ((unsigned)f2bf(v1.y) << 16);
    pk.w = (unsigned)f2bf(v1.z) | ((unsigned)f2bf(v1.w) << 16);
    *(uint4*)(lsAc + aoff) = pk;

    __syncthreads();

    // ---- compute: 2 k-halves x 4x4 frags
#pragma unroll
    for (int kh = 0; kh < 2; kh++) {
      short8 af[4], bf[4];
#pragma unroll
      for (int fr = 0; fr < 4; fr++) {
        int row = fr * 16 + (lane & 15);
        unsigned int lg = (unsigned)(row * 128 + kh * 64 + (lane >> 4) * 16);
        af[fr] = *(const short8*)(lsAc + SWZ(lg, row));
      }
#pragma unroll
      for (int fc = 0; fc < 4; fc++) {
        int col = colbase + fc * 16 + (lane & 15);
        unsigned int lg = (unsigned)(col * 128 + kh * 64 + (lane >> 4) * 16);
        bf[fc] = *(const short8*)(lsBc + SWZ(lg, col));
      }
#pragma unroll
      for (int fr = 0; fr < 4; fr++)
#pragma unroll
        for (int fc = 0; fc < 4; fc++)
          acc[fr][fc] = __builtin_amdgcn_mfma_f32_16x16x32_bf16(af[fr], bf[fc], acc[fr][fc], 0, 0, 0);
    }
    __syncthreads();
  }

  // ---- epilogue: score = sum_u tanh(acc + qp[u]) * Wv[u]
  const int rgrp = lane >> 4;
  const int cl = lane & 15;
  float ps[4][4];
#pragma unroll
  for (int fr = 0; fr < 4; fr++)
#pragma unroll
    for (int r = 0; r < 4; r++) ps[fr][r] = 0.f;

#pragma unroll
  for (int fc = 0; fc < 4; fc++) {
    int u = colbase + fc * 16 + cl;
    float qpu = qp[u], wvu = wv_s[u];
#pragma unroll
    for (int fr = 0; fr < 4; fr++)
#pragma unroll
      for (int r = 0; r < 4; r++)
        ps[fr][r] = fmaf(tanh_fast(acc[fr][fc][r] + qpu), wvu, ps[fr][r]);
  }
#pragma unroll
  for (int fr = 0; fr < 4; fr++)
#pragma unroll
    for (int r = 0; r < 4; r++) {
      float v = ps[fr][r];
      v += __shfl_xor(v, 1, 64);
      v += __shfl_xor(v, 2, 64);
      v += __shfl_xor(v, 4, 64);
      v += __shfl_xor(v, 8, 64);
      if (cl == 0) red[(fr * 16 + rgrp * 4 + r) * 8 + wid] = v;
    }
  __syncthreads();
  if (tid < 64) {
    float s = bv[0];
#pragma unroll
    for (int w = 0; w < 8; w++) s += red[tid * 8 + w];
    if (!rowflag[tid]) s = -INFINITY;
    scores[m0 + tid] = s;
  }
}

// ---------------- masked softmax over T per batch ----------------
__global__ __launch_bounds__(256) void k_softmax(const float* __restrict__ scores,
                                                 float* __restrict__ attn) {
  const int b = blockIdx.x, tid = threadIdx.x;
  const float* srow = scores + (size_t)b * T_;
  float s[8];
  float m = -INFINITY;
#pragma unroll
  for (int j = 0; j < 8; j++) {
    s[j] = srow[tid + 256 * j];
    m = fmaxf(m, s[j]);
  }
#pragma unroll
  for (int o = 1; o < 64; o <<= 1) m = fmaxf(m, __shfl_xor(m, o, 64));
  __shared__ float redm[4], redsum[4];
  if ((tid & 63) == 0) redm[tid >> 6] = m;
  __syncthreads();
  m = fmaxf(fmaxf(redm[0], redm[1]), fmaxf(redm[2], redm[3]));
  float sum = 0.f;
#pragma unroll
  for (int j = 0; j < 8; j++) {
    s[j] = __expf(s[j] - m);
    sum += s[j];
  }
#pragma unroll
  for (int o = 1; o < 64; o <<= 1) sum += __shfl_xor(sum, o, 64);
  if ((tid & 63) == 0) redsum[tid >> 6] = sum;
  __syncthreads();
  sum = redsum[0] + redsum[1] + redsum[2] + redsum[3];
  float inv = 1.f / sum;
#pragma unroll
  for (int j = 0; j < 8; j++) attn[(size_t)b * T_ + tid + 256 * j] = s[j] * inv;
}

// ---------------- context partial: per (b, t-chunk of 128) ----------------
__global__ __launch_bounds__(128) void k_ctx_part(const float* __restrict__ values,
                                                  const float* __restrict__ attn,
                                                  float* __restrict__ part) {
  const int tc = blockIdx.x, b = blockIdx.y;
  const int tid = threadIdx.x;
  const float4* vp = (const float4*)(values + ((size_t)b * T_ + tc * 128) * D_);
  const float* ap = attn + (size_t)b * T_ + tc * 128;
  float4 acc = {0.f, 0.f, 0.f, 0.f};
#pragma unroll 4
  for (int t = 0; t < 128; t++) {
    float w = ap[t];
    float4 v = vp[(size_t)t * 128 + tid];
    acc.x = fmaf(w, v.x, acc.x);
    acc.y = fmaf(w, v.y, acc.y);
    acc.z = fmaf(w, v.z, acc.z);
    acc.w = fmaf(w, v.w, acc.w);
  }
  float4* pp = (float4*)(part + (size_t)(b * 16 + tc) * D_);
  pp[tid] = acc;
}

// ---------------- context reduce over 16 t-chunks ----------------
__global__ __launch_bounds__(256) void k_ctx_reduce(const float* __restrict__ part,
                                                    float* __restrict__ ctx) {
  const int gid = blockIdx.x * 256 + threadIdx.x;  // 0..32767
  const int b = gid >> 9, d = gid & 511;
  float s = 0.f;
#pragma unroll
  for (int tc = 0; tc < 16; tc++) s += part[(size_t)(b * 16 + tc) * D_ + d];
  ctx[gid] = s;
}

extern "C" void kernel_launch(void* const* d_in, const int* in_sizes, int n_in,
                              void* d_out, int out_size, void* d_ws, size_t ws_size,
                              hipStream_t stream) {
  const float* query  = (const float*)d_in[0];
  const float* values = (const float*)d_in[1];
  const float* W1     = (const float*)d_in[2];
  const float* b1     = (const float*)d_in[3];
  const float* W2     = (const float*)d_in[4];
  const float* b2     = (const float*)d_in[5];
  const float* Wv     = (const float*)d_in[6];
  const float* bv     = (const float*)d_in[7];

  float* out_ctx = (float*)d_out;                 // [64,512]
  float* out_attn = out_ctx + B_ * D_;            // [64,2048]

  char* ws = (char*)d_ws;
  float* qproj          = (float*)ws;                        // 128 KB
  unsigned short* w2t   = (unsigned short*)(ws + (128 << 10)); // 512 KB
  float* scores         = (float*)(ws + (640 << 10));        // 512 KB
  float* part           = (float*)(ws + (1152 << 10));       // 2 MB

  k_qproj<<<dim3(B_), dim3(256), 0, stream>>>(query, W1, b1, qproj);
  k_w2t<<<dim3(16, 16), dim3(32, 8), 0, stream>>>(W2, w2t);
  k_score<<<dim3((B_ * T_) / 64), dim3(512), 0, stream>>>(values, w2t, qproj, b2, Wv, bv, scores);
  k_softmax<<<dim3(B_), dim3(256), 0, stream>>>(scores, out_attn);
  k_ctx_part<<<dim3(16, B_), dim3(128), 0, stream>>>(values, out_attn, part);
  k_ctx_reduce<<<dim3(128), dim3(256), 0, stream>>>(part, out_ctx);
}